// Round 17
// baseline (195.244 us; speedup 1.0000x reference)
//
#include <hip/hip_runtime.h>
#include <stdint.h>

// ---------------- types / helpers ----------------
typedef float  f32x4  __attribute__((ext_vector_type(4)));
typedef short  bf16x8 __attribute__((ext_vector_type(8)));

#define NCOL 800    // L*NH output cols of o_h
#define NPAD 896    // padded to 7*128
#define KDIM 6400   // L*D
#define KFC  1856   // fc K = 1824 padded to 29*64

__device__ __forceinline__ unsigned short f2bf(float f) {
  unsigned int u = __float_as_uint(f);
  return (unsigned short)((u + 0x7FFFu + ((u >> 16) & 1u)) >> 16);  // RNE
}
__device__ __forceinline__ float bf2f(unsigned short s) {
  return __uint_as_float(((unsigned int)s) << 16);
}
__device__ __forceinline__ void gload16(const void* g, void* lds) {
  __builtin_amdgcn_global_load_lds(
      (const __attribute__((address_space(1))) unsigned int*)g,
      (__attribute__((address_space(3))) unsigned int*)lds, 16, 0, 0);
}
// HW barrier that is ALSO a compiler memory fence (asm memory clobber).
__device__ __forceinline__ void barrier_fenced() {
  __builtin_amdgcn_sched_barrier(0);
  asm volatile("s_barrier" ::: "memory");
  __builtin_amdgcn_sched_barrier(0);
}
__device__ __forceinline__ void wait_vm0() {
  asm volatile("s_waitcnt vmcnt(0)" ::: "memory");
}

// ---------------- K1: merged prep — gather_e | pack_w | pack_fcwT ----------------
__global__ void k_prep(const int* __restrict__ iseq, const float* __restrict__ iemb,
                       unsigned short* __restrict__ Ebf,
                       const float* __restrict__ Wh, unsigned short* __restrict__ Wbf,
                       const float* __restrict__ fcW, unsigned short* __restrict__ Bt) {
  __shared__ float tile[32][33];
  const int blk = blockIdx.x;
  if (blk < 1024) {
    int b = blk;
    for (int idx = threadIdx.x; idx < 1600; idx += 256) {  // 50 rows * 32 float4
      int tt = idx >> 5, dq = idx & 31;
      int row = iseq[b * 50 + tt];
      float4 v = *reinterpret_cast<const float4*>(iemb + (size_t)row * 128 + dq * 4);
      unsigned int lo = (unsigned int)f2bf(v.x) | ((unsigned int)f2bf(v.y) << 16);
      unsigned int hi = (unsigned int)f2bf(v.z) | ((unsigned int)f2bf(v.w) << 16);
      *reinterpret_cast<uint2*>(Ebf + (size_t)b * KDIM + tt * 128 + dq * 4) = make_uint2(lo, hi);
    }
  } else if (blk < 1024 + NPAD) {
    int n = blk - 1024;
    unsigned short* dst = Wbf + (size_t)n * KDIM;
    if (n >= NCOL) {
      uint4 z = make_uint4(0, 0, 0, 0);
      for (int idx = threadIdx.x; idx < KDIM / 8; idx += 256)
        reinterpret_cast<uint4*>(dst)[idx] = z;
    } else {
      const float* src = Wh + (size_t)n * KDIM;  // pure row copy: ((l*16+h)*50+i)*128+d == n*6400+k
      for (int idx = threadIdx.x; idx < KDIM / 4; idx += 256) {
        float4 v = reinterpret_cast<const float4*>(src)[idx];
        unsigned int lo = (unsigned int)f2bf(v.x) | ((unsigned int)f2bf(v.y) << 16);
        unsigned int hi = (unsigned int)f2bf(v.z) | ((unsigned int)f2bf(v.w) << 16);
        reinterpret_cast<uint2*>(dst)[idx] = make_uint2(lo, hi);
      }
    }
  } else {
    int idx = blk - 1024 - NPAD;       // 0..231
    int k0 = (idx % 58) * 32, d0 = (idx / 58) * 32;
    int tx = threadIdx.x & 31, ty = threadIdx.x >> 5;  // 32 x 8
#pragma unroll
    for (int it = 0; it < 4; it++) {
      int k = k0 + ty + it * 8;
      tile[ty + it * 8][tx] = (k < 1824) ? fcW[(size_t)k * 128 + d0 + tx] : 0.f;
    }
    __syncthreads();
#pragma unroll
    for (int it = 0; it < 4; it++) {
      int d = d0 + ty + it * 8;
      Bt[(size_t)d * KFC + k0 + tx] = f2bf(tile[tx][ty + it * 8]);
    }
  }
}

// ---------------- K2: conv-as-shifted-GEMM, BM=256 ----------------
// R15 lesson: (512,4) = 8 waves/SIMD = 64-VGPR cap -> acc spilled (VGPR=60,
// WRITE 30->82MB, 153us). Need ~110 regs -> (512,2) = 4 waves/SIMD = 128-VGPR cap.
// BM=256 stages 48KB/K-step for 2x output: 1.48 GB total L2->LDS (62.5% cut vs
// BM=128's 4.04 GB @ ~30 TB/s = L2-bound). MfmaUtil already 36% even spilled.
// XCD locality: grid.x=8, mt=bx&3, s=2*bz+(bx>>2) -> XCD=bx; each XCD owns one
// 3.3MB A-slice (L2-resident). 728 blocks, heavy (low-s) first.
__launch_bounds__(512, 2)
__global__ void k_conv(const unsigned short* __restrict__ Ebf,
                       const unsigned short* __restrict__ Wbf,
                       const float* __restrict__ bh,
                       unsigned int* __restrict__ o_h) {
  __shared__ alignas(16) unsigned short As[256 * 64];   // 32 KB
  __shared__ alignas(16) unsigned short Bs[128 * 64];   // 16 KB

  const int tid = threadIdx.x;
  const int wid = tid >> 6, lane = tid & 63;
  const int r = lane & 15, kg = lane >> 4;
  const int wm = wid >> 1, wn = wid & 1;
  const int bx = blockIdx.x, nt = blockIdx.y, bz = blockIdx.z;
  const int mt = bx & 3;
  const int s = 2 * bz + (bx >> 2);

  const int lmax = min(nt * 8 + 7, 49);
  const int shi = 49 - nt * 8;           // max valid s for this n-tile
  if (s > shi) return;

  const int Rloc = tid >> 3;    // staging: row-in-64 per thread (0..63)
  const int cph = tid & 7;      // staging: physical 16B chunk per thread

  const f32x4 z4 = {0.f, 0.f, 0.f, 0.f};
  f32x4 acc[4][4];
#pragma unroll
  for (int m = 0; m < 4; m++)
#pragma unroll
    for (int n = 0; n < 4; n++) acc[m][n] = z4;

  // swizzled staging: LDS phys chunk p of row R holds logical chunk (p ^ (R&7)).
  auto STAGE = [&](int kk) {
#pragma unroll
    for (int ia = 0; ia < 4; ia++) {             // A: 256 rows, 64/call
      int R = ia * 64 + Rloc;
      const unsigned short* src = Ebf + (size_t)(mt * 256 + R) * KDIM + s * 128 + kk * 64
                                      + ((cph ^ (R & 7)) * 8);
      gload16(src, &As[(ia * 64 + wid * 8) * 64]);
    }
#pragma unroll
    for (int ib = 0; ib < 2; ib++) {             // B: 128 rows, 64/call
      int R = ib * 64 + Rloc;
      const unsigned short* src = Wbf + (size_t)(nt * 128 + R) * KDIM + kk * 64
                                      + ((cph ^ (R & 7)) * 8);
      gload16(src, &Bs[(ib * 64 + wid * 8) * 64]);
    }
  };

  auto COMPUTE = [&]() {
#pragma unroll
    for (int ks = 0; ks < 2; ks++) {
      bf16x8 af[4], bfr[4];
      const int sw = ((ks * 4 + kg) ^ (r & 7)) * 8;  // swizzled read offset (shorts)
#pragma unroll
      for (int m = 0; m < 4; m++)
        af[m] = *reinterpret_cast<const bf16x8*>(&As[(wm * 64 + m * 16 + r) * 64 + sw]);
#pragma unroll
      for (int n = 0; n < 4; n++)
        bfr[n] = *reinterpret_cast<const bf16x8*>(&Bs[(wn * 64 + n * 16 + r) * 64 + sw]);
#pragma unroll
      for (int m = 0; m < 4; m++)
#pragma unroll
        for (int n = 0; n < 4; n++)
          acc[m][n] = __builtin_amdgcn_mfma_f32_16x16x32_bf16(af[m], bfr[n], acc[m][n], 0, 0, 0);
    }
  };

  const int nk = min(50 - s, lmax + 1) * 2;  // BK-steps (zero-masked i>l terms are free/correct)
  for (int kk = 0; kk < nk; kk++) {
    STAGE(kk);
    __syncthreads();
    COMPUTE();
    __syncthreads();
  }

  // fused epilogue: relu(conv+bh), validity mask, one atomicMax per element
#pragma unroll
  for (int n = 0; n < 4; n++) {
    int ng = nt * 128 + wn * 64 + n * 16 + r;
    if (ng < NCOL && s <= 49 - (ng >> 4)) {
      float bhv = bh[ng];
#pragma unroll
      for (int m = 0; m < 4; m++) {
        int b = mt * 256 + wm * 64 + m * 16 + kg * 4;
#pragma unroll
        for (int q = 0; q < 4; q++) {
          float v = fmaxf(acc[m][n][q] + bhv, 0.f);
          atomicMax(&o_h[(size_t)(b + q) * NCOL + ng], __float_as_uint(v));
        }
      }
    }
  }
}

// ---------------- K2v: fused o_v compute + o_h convert -> o_bf rows ----------------
__global__ void k_ovcvt(const unsigned short* __restrict__ Ebf,
                        const float* __restrict__ Wv, const float* __restrict__ bv,
                        const unsigned int* __restrict__ o_h,
                        unsigned short* __restrict__ o_bf) {
  int b = blockIdx.x;
  const unsigned short* e = Ebf + (size_t)b * KDIM;
  // part 1: o_bf[b][0:1024] = bf16(sum_t E*Wv + bv)
  for (int rep = 0; rep < 2; rep++) {
    int idx2 = rep * 256 + threadIdx.x;   // uint index, 0..511
    int v = idx2 >> 6;
    int dp = (idx2 & 63) * 2;
    float a0 = bv[v], a1 = a0;
    for (int tt = 0; tt < 50; tt++) {
      float w = Wv[v * 50 + tt];
      a0 += bf2f(e[tt * 128 + dp]) * w;
      a1 += bf2f(e[tt * 128 + dp + 1]) * w;
    }
    unsigned int pk = (unsigned int)f2bf(a0) | ((unsigned int)f2bf(a1) << 16);
    reinterpret_cast<unsigned int*>(o_bf + (size_t)b * KFC)[idx2] = pk;
  }
  // part 2: o_bf[b][1024:1856] = bf16(o_h), zero-padded past 800
  const unsigned int* src = o_h + (size_t)b * NCOL;
  unsigned int* dst = reinterpret_cast<unsigned int*>(o_bf + (size_t)b * KFC + 1024);
  for (int i = threadIdx.x; i < 416; i += 256) {
    int j0 = 2 * i, j1 = j0 + 1;
    unsigned int lo = (j0 < NCOL) ? f2bf(__uint_as_float(src[j0])) : 0;
    unsigned int hi = (j1 < NCOL) ? f2bf(__uint_as_float(src[j1])) : 0;
    dst[i] = lo | (hi << 16);
  }
}

// ---------------- K3: fc partial GEMM, K-split x4, atomicAdd f32 partials ----------------
__launch_bounds__(256, 2)
__global__ void k_fc2(const unsigned short* __restrict__ o_bf,
                      const unsigned short* __restrict__ Bt,
                      float* __restrict__ facc) {
  __shared__ alignas(16) unsigned short As[2][128 * 64];
  __shared__ alignas(16) unsigned short Bs[2][128 * 64];

  const int tid = threadIdx.x;
  const int wid = tid >> 6, lane = tid & 63;
  const int r = lane & 15, kg = lane >> 4;
  const int wm = wid >> 1, wn = wid & 1;
  const int mt = blockIdx.x, kc = blockIdx.y;
  const int kk0 = kc * 8;
  const int nstep = (kc < 3) ? 8 : 5;  // 29 total K-steps

  const int Rloc = lane >> 3;
  const int cph = lane & 7;

  const f32x4 z4 = {0.f, 0.f, 0.f, 0.f};
  f32x4 acc[4][4];
#pragma unroll
  for (int m = 0; m < 4; m++)
#pragma unroll
    for (int n = 0; n < 4; n++) acc[m][n] = z4;

  auto STAGE = [&](int buf, int kk) {
    const int Rb = wid * 32;
#pragma unroll
    for (int ia = 0; ia < 4; ia++) {
      int R = Rb + ia * 8 + Rloc;
      const unsigned short* src = o_bf + (size_t)(mt * 128 + R) * KFC + kk * 64
                                       + ((cph ^ (R & 7)) * 8);
      gload16(src, &As[buf][(Rb + ia * 8) * 64]);
    }
#pragma unroll
    for (int ia = 0; ia < 4; ia++) {
      int R = Rb + ia * 8 + Rloc;
      const unsigned short* src = Bt + (size_t)R * KFC + kk * 64 + ((cph ^ (R & 7)) * 8);
      gload16(src, &Bs[buf][(Rb + ia * 8) * 64]);
    }
  };

  auto COMPUTE = [&](int buf) {
#pragma unroll
    for (int ks = 0; ks < 2; ks++) {
      bf16x8 af[4], bfr[4];
      const int sw = ((ks * 4 + kg) ^ (r & 7)) * 8;
#pragma unroll
      for (int m = 0; m < 4; m++)
        af[m] = *reinterpret_cast<const bf16x8*>(&As[buf][(wm * 64 + m * 16 + r) * 64 + sw]);
#pragma unroll
      for (int n = 0; n < 4; n++)
        bfr[n] = *reinterpret_cast<const bf16x8*>(&Bs[buf][(wn * 64 + n * 16 + r) * 64 + sw]);
#pragma unroll
      for (int m = 0; m < 4; m++)
#pragma unroll
        for (int n = 0; n < 4; n++)
          acc[m][n] = __builtin_amdgcn_mfma_f32_16x16x32_bf16(af[m], bfr[n], acc[m][n], 0, 0, 0);
    }
  };

  int cur = 0;
  STAGE(0, kk0);
  wait_vm0();
  barrier_fenced();
  for (int t = 0; t < nstep; t++) {
    bool has_next = (t + 1 < nstep);
    if (has_next) STAGE(cur ^ 1, kk0 + t + 1);
    __builtin_amdgcn_s_setprio(1);
    COMPUTE(cur);
    __builtin_amdgcn_s_setprio(0);
    wait_vm0();
    barrier_fenced();
    cur ^= 1;
  }

#pragma unroll
  for (int m = 0; m < 4; m++) {
    int b = mt * 128 + wm * 64 + m * 16 + kg * 4;
#pragma unroll
    for (int n = 0; n < 4; n++) {
      int d = wn * 64 + n * 16 + r;
#pragma unroll
      for (int q = 0; q < 4; q++)
        atomicAdd(&facc[(size_t)(b + q) * 128 + d], acc[m][n][q]);
    }
  }
}

// ---------------- K4: finalize fc (bias+relu) + P_u copy, fused ----------------
__global__ void k_fin(const float* __restrict__ facc, const float* __restrict__ fcb,
                      const int* __restrict__ uid, const float* __restrict__ uemb,
                      float* __restrict__ out) {
  int idx = blockIdx.x * 256 + threadIdx.x;  // 1024*256 elems of out
  int b = idx >> 8, c = idx & 255;
  float v;
  if (c < 128) v = fmaxf(facc[(size_t)b * 128 + c] + fcb[c], 0.f);
  else         v = uemb[(size_t)uid[b] * 128 + (c - 128)];
  out[idx] = v;
}

// ---------------- launch ----------------
extern "C" void kernel_launch(void* const* d_in, const int* in_sizes, int n_in,
                              void* d_out, int out_size, void* d_ws, size_t ws_size,
                              hipStream_t stream) {
  const int*   uid  = (const int*)d_in[0];
  const int*   iseq = (const int*)d_in[1];
  const float* uemb = (const float*)d_in[2];
  const float* iemb = (const float*)d_in[3];
  const float* Wv   = (const float*)d_in[4];
  const float* bv   = (const float*)d_in[5];
  const float* Wh   = (const float*)d_in[6];
  const float* bh   = (const float*)d_in[7];
  const float* fcW  = (const float*)d_in[8];
  const float* fcb  = (const float*)d_in[9];
  float* out = (float*)d_out;
  char* ws = (char*)d_ws;

  // layout (28.9 MB peak). o_bf aliases Wbf (written only after k_conv).
  // facc and Bt OUTSIDE Wbf (facc is RMW; Bt written by k_prep while Wbf live).
  unsigned int*   o_h  = (unsigned int*)(ws);                 //  3,276,800 B
  unsigned short* Ebf  = (unsigned short*)(ws + 3276800);     // 13,107,200 B -> 16,384,000
  unsigned short* Wbf  = (unsigned short*)(ws + 16384000);    // 11,468,800 B -> 27,852,800
  unsigned short* o_bf = (unsigned short*)(ws + 16384000);    //  3,801,088 B (alias Wbf, OK)
  float*          facc = (float*)(ws + 27852800);             //    524,288 B -> 28,377,088
  unsigned short* Bt   = (unsigned short*)(ws + 28377088);    //    475,136 B -> 28,852,224

  hipMemsetAsync(o_h, 0, (size_t)1024 * NCOL * 4, stream);
  hipMemsetAsync(facc, 0, (size_t)1024 * 128 * 4, stream);
  k_prep  <<<dim3(1024 + NPAD + 232), 256, 0, stream>>>(iseq, iemb, Ebf, Wh, Wbf, fcW, Bt);
  k_conv  <<<dim3(8, 7, 25), 512, 0, stream>>>(Ebf, Wbf, bh, o_h);
  k_ovcvt <<<dim3(1024), 256, 0, stream>>>(Ebf, Wv, bv, o_h, o_bf);  // o_bf aliases Wbf (dead)
  k_fc2   <<<dim3(8, 4), 256, 0, stream>>>(o_bf, Bt, facc);
  k_fin   <<<dim3(1024), 256, 0, stream>>>(facc, fcb, uid, uemb, out);
}

// Round 18
// 191.188 us; speedup vs baseline: 1.0212x; 1.0212x over previous
//
#include <hip/hip_runtime.h>
#include <stdint.h>

// ---------------- types / helpers ----------------
typedef float  f32x4  __attribute__((ext_vector_type(4)));
typedef short  bf16x8 __attribute__((ext_vector_type(8)));

#define NCOL 800    // L*NH output cols of o_h
#define NPAD 896    // padded to 7*128
#define KDIM 6400   // L*D
#define KFC  1856   // fc K = 1824 padded to 29*64
#define OHP  819200 // 1024*800: one parity copy of o_h (uints)

__device__ __forceinline__ unsigned short f2bf(float f) {
  unsigned int u = __float_as_uint(f);
  return (unsigned short)((u + 0x7FFFu + ((u >> 16) & 1u)) >> 16);  // RNE
}
__device__ __forceinline__ float bf2f(unsigned short s) {
  return __uint_as_float(((unsigned int)s) << 16);
}
__device__ __forceinline__ void gload16(const void* g, void* lds) {
  __builtin_amdgcn_global_load_lds(
      (const __attribute__((address_space(1))) unsigned int*)g,
      (__attribute__((address_space(3))) unsigned int*)lds, 16, 0, 0);
}
// HW barrier that is ALSO a compiler memory fence (asm memory clobber).
__device__ __forceinline__ void barrier_fenced() {
  __builtin_amdgcn_sched_barrier(0);
  asm volatile("s_barrier" ::: "memory");
  __builtin_amdgcn_sched_barrier(0);
}
__device__ __forceinline__ void wait_vm0() {
  asm volatile("s_waitcnt vmcnt(0)" ::: "memory");
}

// ---------------- K1: merged prep — gather_e | pack_w ----------------
__global__ void k_prep(const int* __restrict__ iseq, const float* __restrict__ iemb,
                       unsigned short* __restrict__ Ebf,
                       const float* __restrict__ Wh, unsigned short* __restrict__ Wbf) {
  const int blk = blockIdx.x;
  if (blk < 1024) {
    int b = blk;
    for (int idx = threadIdx.x; idx < 1600; idx += 256) {  // 50 rows * 32 float4
      int tt = idx >> 5, dq = idx & 31;
      int row = iseq[b * 50 + tt];
      float4 v = *reinterpret_cast<const float4*>(iemb + (size_t)row * 128 + dq * 4);
      unsigned int lo = (unsigned int)f2bf(v.x) | ((unsigned int)f2bf(v.y) << 16);
      unsigned int hi = (unsigned int)f2bf(v.z) | ((unsigned int)f2bf(v.w) << 16);
      *reinterpret_cast<uint2*>(Ebf + (size_t)b * KDIM + tt * 128 + dq * 4) = make_uint2(lo, hi);
    }
  } else {
    int n = blk - 1024;
    unsigned short* dst = Wbf + (size_t)n * KDIM;
    if (n >= NCOL) {
      uint4 z = make_uint4(0, 0, 0, 0);
      for (int idx = threadIdx.x; idx < KDIM / 8; idx += 256)
        reinterpret_cast<uint4*>(dst)[idx] = z;
    } else {
      const float* src = Wh + (size_t)n * KDIM;  // pure row copy: ((l*16+h)*50+i)*128+d == n*6400+k
      for (int idx = threadIdx.x; idx < KDIM / 4; idx += 256) {
        float4 v = reinterpret_cast<const float4*>(src)[idx];
        unsigned int lo = (unsigned int)f2bf(v.x) | ((unsigned int)f2bf(v.y) << 16);
        unsigned int hi = (unsigned int)f2bf(v.z) | ((unsigned int)f2bf(v.w) << 16);
        reinterpret_cast<uint2*>(dst)[idx] = make_uint2(lo, hi);
      }
    }
  }
}

// ---------------- K2: conv-as-shifted-GEMM, BM=256, parity-split o_h ----------------
// R16 diagnosis: mt=bx&3 put two XCDs (bx, bx+4) on the SAME o_h slice ->
// cross-XCD-shared lines force device-scope atomics to write through the fabric
// (WRITE 81.6MB == 20.9M atomics x 4B exactly). Fix: split o_h by s-parity
// (par = bx>>2) -> XCD bx exclusively owns o_hp[par][mt*256..mt*256+255][*]
// (800KB, L2-resident) -> atomics coalesce in L2 like R13 (WRITE 30MB).
// BM=256 keeps the staging cut (48KB/K-step for 2x output; MfmaUtil 36% proven).
__launch_bounds__(512, 2)
__global__ void k_conv(const unsigned short* __restrict__ Ebf,
                       const unsigned short* __restrict__ Wbf,
                       const float* __restrict__ bh,
                       unsigned int* __restrict__ o_hp) {
  __shared__ alignas(16) unsigned short As[256 * 64];   // 32 KB
  __shared__ alignas(16) unsigned short Bs[128 * 64];   // 16 KB

  const int tid = threadIdx.x;
  const int wid = tid >> 6, lane = tid & 63;
  const int r = lane & 15, kg = lane >> 4;
  const int wm = wid >> 1, wn = wid & 1;
  const int bx = blockIdx.x, nt = blockIdx.y, bz = blockIdx.z;
  const int mt = bx & 3;
  const int par = bx >> 2;
  const int s = 2 * bz + par;

  const int lmax = min(nt * 8 + 7, 49);
  const int shi = 49 - nt * 8;           // max valid s for this n-tile
  if (s > shi) return;

  const int Rloc = tid >> 3;    // staging: row-in-64 per thread (0..63)
  const int cph = tid & 7;      // staging: physical 16B chunk per thread

  const f32x4 z4 = {0.f, 0.f, 0.f, 0.f};
  f32x4 acc[4][4];
#pragma unroll
  for (int m = 0; m < 4; m++)
#pragma unroll
    for (int n = 0; n < 4; n++) acc[m][n] = z4;

  // swizzled staging: LDS phys chunk p of row R holds logical chunk (p ^ (R&7)).
  auto STAGE = [&](int kk) {
#pragma unroll
    for (int ia = 0; ia < 4; ia++) {             // A: 256 rows, 64/call
      int R = ia * 64 + Rloc;
      const unsigned short* src = Ebf + (size_t)(mt * 256 + R) * KDIM + s * 128 + kk * 64
                                      + ((cph ^ (R & 7)) * 8);
      gload16(src, &As[(ia * 64 + wid * 8) * 64]);
    }
#pragma unroll
    for (int ib = 0; ib < 2; ib++) {             // B: 128 rows, 64/call
      int R = ib * 64 + Rloc;
      const unsigned short* src = Wbf + (size_t)(nt * 128 + R) * KDIM + kk * 64
                                      + ((cph ^ (R & 7)) * 8);
      gload16(src, &Bs[(ib * 64 + wid * 8) * 64]);
    }
  };

  auto COMPUTE = [&]() {
#pragma unroll
    for (int ks = 0; ks < 2; ks++) {
      bf16x8 af[4], bfr[4];
      const int sw = ((ks * 4 + kg) ^ (r & 7)) * 8;  // swizzled read offset (shorts)
#pragma unroll
      for (int m = 0; m < 4; m++)
        af[m] = *reinterpret_cast<const bf16x8*>(&As[(wm * 64 + m * 16 + r) * 64 + sw]);
#pragma unroll
      for (int n = 0; n < 4; n++)
        bfr[n] = *reinterpret_cast<const bf16x8*>(&Bs[(wn * 64 + n * 16 + r) * 64 + sw]);
#pragma unroll
      for (int m = 0; m < 4; m++)
#pragma unroll
        for (int n = 0; n < 4; n++)
          acc[m][n] = __builtin_amdgcn_mfma_f32_16x16x32_bf16(af[m], bfr[n], acc[m][n], 0, 0, 0);
    }
  };

  const int nk = min(50 - s, lmax + 1) * 2;  // BK-steps (zero-masked i>l terms are free/correct)
  for (int kk = 0; kk < nk; kk++) {
    STAGE(kk);
    __syncthreads();
    COMPUTE();
    __syncthreads();
  }

  // fused epilogue: relu(conv+bh), validity mask, atomicMax into THIS PARITY's buffer
  unsigned int* o_h = o_hp + (size_t)par * OHP;
#pragma unroll
  for (int n = 0; n < 4; n++) {
    int ng = nt * 128 + wn * 64 + n * 16 + r;
    if (ng < NCOL && s <= 49 - (ng >> 4)) {
      float bhv = bh[ng];
#pragma unroll
      for (int m = 0; m < 4; m++) {
        int b = mt * 256 + wm * 64 + m * 16 + kg * 4;
#pragma unroll
        for (int q = 0; q < 4; q++) {
          float v = fmaxf(acc[m][n][q] + bhv, 0.f);
          atomicMax(&o_h[(size_t)(b + q) * NCOL + ng], __float_as_uint(v));
        }
      }
    }
  }
}

// ---------------- K2v: o_v compute + parity-merge o_h convert + fcW transpose ----------------
// blocks [0,1024): per-batch o_bf row (o_v part + max(o_hp[0],o_hp[1]) -> bf16)
// blocks [1024,1256): Bt[d][k] = bf16(fcW[k][d]) (Wbf dead now -> Bt aliases it)
__global__ void k_ovcvt(const unsigned short* __restrict__ Ebf,
                        const float* __restrict__ Wv, const float* __restrict__ bv,
                        const unsigned int* __restrict__ o_hp,
                        unsigned short* __restrict__ o_bf,
                        const float* __restrict__ fcW, unsigned short* __restrict__ Bt) {
  __shared__ float tile[32][33];
  const int blk = blockIdx.x;
  if (blk < 1024) {
    int b = blk;
    const unsigned short* e = Ebf + (size_t)b * KDIM;
    // part 1: o_bf[b][0:1024] = bf16(sum_t E*Wv + bv)
    for (int rep = 0; rep < 2; rep++) {
      int idx2 = rep * 256 + threadIdx.x;   // uint index, 0..511
      int v = idx2 >> 6;
      int dp = (idx2 & 63) * 2;
      float a0 = bv[v], a1 = a0;
      for (int tt = 0; tt < 50; tt++) {
        float w = Wv[v * 50 + tt];
        a0 += bf2f(e[tt * 128 + dp]) * w;
        a1 += bf2f(e[tt * 128 + dp + 1]) * w;
      }
      unsigned int pk = (unsigned int)f2bf(a0) | ((unsigned int)f2bf(a1) << 16);
      reinterpret_cast<unsigned int*>(o_bf + (size_t)b * KFC)[idx2] = pk;
    }
    // part 2: o_bf[b][1024:1856] = bf16(max(o_hp[0],o_hp[1])), zero-pad past 800
    // (uint max == float max for non-negative floats)
    const unsigned int* s0 = o_hp + (size_t)b * NCOL;
    const unsigned int* s1 = o_hp + OHP + (size_t)b * NCOL;
    unsigned int* dst = reinterpret_cast<unsigned int*>(o_bf + (size_t)b * KFC + 1024);
    for (int i = threadIdx.x; i < 416; i += 256) {
      int j0 = 2 * i, j1 = j0 + 1;
      unsigned int lo = (j0 < NCOL) ? f2bf(__uint_as_float(max(s0[j0], s1[j0]))) : 0;
      unsigned int hi = (j1 < NCOL) ? f2bf(__uint_as_float(max(s0[j1], s1[j1]))) : 0;
      dst[i] = lo | (hi << 16);
    }
  } else {
    int idx = blk - 1024;              // 0..231
    int k0 = (idx % 58) * 32, d0 = (idx / 58) * 32;
    int tx = threadIdx.x & 31, ty = threadIdx.x >> 5;  // 32 x 8
#pragma unroll
    for (int it = 0; it < 4; it++) {
      int k = k0 + ty + it * 8;
      tile[ty + it * 8][tx] = (k < 1824) ? fcW[(size_t)k * 128 + d0 + tx] : 0.f;
    }
    __syncthreads();
#pragma unroll
    for (int it = 0; it < 4; it++) {
      int d = d0 + ty + it * 8;
      Bt[(size_t)d * KFC + k0 + tx] = f2bf(tile[tx][ty + it * 8]);
    }
  }
}

// ---------------- K3: fc partial GEMM, K-split x4, atomicAdd f32 partials ----------------
__launch_bounds__(256, 2)
__global__ void k_fc2(const unsigned short* __restrict__ o_bf,
                      const unsigned short* __restrict__ Bt,
                      float* __restrict__ facc) {
  __shared__ alignas(16) unsigned short As[2][128 * 64];
  __shared__ alignas(16) unsigned short Bs[2][128 * 64];

  const int tid = threadIdx.x;
  const int wid = tid >> 6, lane = tid & 63;
  const int r = lane & 15, kg = lane >> 4;
  const int wm = wid >> 1, wn = wid & 1;
  const int mt = blockIdx.x, kc = blockIdx.y;
  const int kk0 = kc * 8;
  const int nstep = (kc < 3) ? 8 : 5;  // 29 total K-steps

  const int Rloc = lane >> 3;
  const int cph = lane & 7;

  const f32x4 z4 = {0.f, 0.f, 0.f, 0.f};
  f32x4 acc[4][4];
#pragma unroll
  for (int m = 0; m < 4; m++)
#pragma unroll
    for (int n = 0; n < 4; n++) acc[m][n] = z4;

  auto STAGE = [&](int buf, int kk) {
    const int Rb = wid * 32;
#pragma unroll
    for (int ia = 0; ia < 4; ia++) {
      int R = Rb + ia * 8 + Rloc;
      const unsigned short* src = o_bf + (size_t)(mt * 128 + R) * KFC + kk * 64
                                       + ((cph ^ (R & 7)) * 8);
      gload16(src, &As[buf][(Rb + ia * 8) * 64]);
    }
#pragma unroll
    for (int ia = 0; ia < 4; ia++) {
      int R = Rb + ia * 8 + Rloc;
      const unsigned short* src = Bt + (size_t)R * KFC + kk * 64 + ((cph ^ (R & 7)) * 8);
      gload16(src, &Bs[buf][(Rb + ia * 8) * 64]);
    }
  };

  auto COMPUTE = [&](int buf) {
#pragma unroll
    for (int ks = 0; ks < 2; ks++) {
      bf16x8 af[4], bfr[4];
      const int sw = ((ks * 4 + kg) ^ (r & 7)) * 8;
#pragma unroll
      for (int m = 0; m < 4; m++)
        af[m] = *reinterpret_cast<const bf16x8*>(&As[buf][(wm * 64 + m * 16 + r) * 64 + sw]);
#pragma unroll
      for (int n = 0; n < 4; n++)
        bfr[n] = *reinterpret_cast<const bf16x8*>(&Bs[buf][(wn * 64 + n * 16 + r) * 64 + sw]);
#pragma unroll
      for (int m = 0; m < 4; m++)
#pragma unroll
        for (int n = 0; n < 4; n++)
          acc[m][n] = __builtin_amdgcn_mfma_f32_16x16x32_bf16(af[m], bfr[n], acc[m][n], 0, 0, 0);
    }
  };

  int cur = 0;
  STAGE(0, kk0);
  wait_vm0();
  barrier_fenced();
  for (int t = 0; t < nstep; t++) {
    bool has_next = (t + 1 < nstep);
    if (has_next) STAGE(cur ^ 1, kk0 + t + 1);
    __builtin_amdgcn_s_setprio(1);
    COMPUTE(cur);
    __builtin_amdgcn_s_setprio(0);
    wait_vm0();
    barrier_fenced();
    cur ^= 1;
  }

#pragma unroll
  for (int m = 0; m < 4; m++) {
    int b = mt * 128 + wm * 64 + m * 16 + kg * 4;
#pragma unroll
    for (int n = 0; n < 4; n++) {
      int d = wn * 64 + n * 16 + r;
#pragma unroll
      for (int q = 0; q < 4; q++)
        atomicAdd(&facc[(size_t)(b + q) * 128 + d], acc[m][n][q]);
    }
  }
}

// ---------------- K4: finalize fc (bias+relu) + P_u copy, fused ----------------
__global__ void k_fin(const float* __restrict__ facc, const float* __restrict__ fcb,
                      const int* __restrict__ uid, const float* __restrict__ uemb,
                      float* __restrict__ out) {
  int idx = blockIdx.x * 256 + threadIdx.x;  // 1024*256 elems of out
  int b = idx >> 8, c = idx & 255;
  float v;
  if (c < 128) v = fmaxf(facc[(size_t)b * 128 + c] + fcb[c], 0.f);
  else         v = uemb[(size_t)uid[b] * 128 + (c - 128)];
  out[idx] = v;
}

// ---------------- launch ----------------
extern "C" void kernel_launch(void* const* d_in, const int* in_sizes, int n_in,
                              void* d_out, int out_size, void* d_ws, size_t ws_size,
                              hipStream_t stream) {
  const int*   uid  = (const int*)d_in[0];
  const int*   iseq = (const int*)d_in[1];
  const float* uemb = (const float*)d_in[2];
  const float* iemb = (const float*)d_in[3];
  const float* Wv   = (const float*)d_in[4];
  const float* bv   = (const float*)d_in[5];
  const float* Wh   = (const float*)d_in[6];
  const float* bh   = (const float*)d_in[7];
  const float* fcW  = (const float*)d_in[8];
  const float* fcb  = (const float*)d_in[9];
  float* out = (float*)d_out;
  char* ws = (char*)d_ws;

  // layout (30.2 MB peak, < R0-proven 32.05).
  // o_hp: 2 parity copies (dead after k_ovcvt). o_bf+Bt alias Wbf — BOTH written
  // only in k_ovcvt, after k_conv's last read of Wbf. facc outside (RMW).
  unsigned int*   o_hp = (unsigned int*)(ws);                 //  6,553,600 B
  unsigned short* Ebf  = (unsigned short*)(ws + 6553600);     // 13,107,200 B -> 19,660,800
  unsigned short* Wbf  = (unsigned short*)(ws + 19660800);    // 11,468,800 B -> 31,129,600
  unsigned short* o_bf = (unsigned short*)(ws + 19660800);    //  3,801,088 B (alias Wbf)
  unsigned short* Bt   = (unsigned short*)(ws + 23461888);    //    475,136 B (alias Wbf)
  float*          facc = (float*)(ws + 31129600);             //    524,288 B -> 31,653,888

  hipMemsetAsync(o_hp, 0, (size_t)2 * OHP * 4, stream);
  hipMemsetAsync(facc, 0, (size_t)1024 * 128 * 4, stream);
  k_prep  <<<dim3(1024 + NPAD), 256, 0, stream>>>(iseq, iemb, Ebf, Wh, Wbf);
  k_conv  <<<dim3(8, 7, 25), 512, 0, stream>>>(Ebf, Wbf, bh, o_hp);
  k_ovcvt <<<dim3(1024 + 232), 256, 0, stream>>>(Ebf, Wv, bv, o_hp, o_bf, fcW, Bt);
  k_fc2   <<<dim3(8, 4), 256, 0, stream>>>(o_bf, Bt, facc);
  k_fin   <<<dim3(1024), 256, 0, stream>>>(facc, fcb, uid, uemb, out);
}

// Round 19
// 190.302 us; speedup vs baseline: 1.0260x; 1.0047x over previous
//
#include <hip/hip_runtime.h>
#include <stdint.h>

// ---------------- types / helpers ----------------
typedef float  f32x4  __attribute__((ext_vector_type(4)));
typedef short  bf16x8 __attribute__((ext_vector_type(8)));

#define NCOL 800    // L*NH output cols of o_h
#define NPAD 896    // padded to 7*128
#define KDIM 6400   // L*D
#define KFC  1856   // fc K = 1824 padded to 29*64

__device__ __forceinline__ unsigned short f2bf(float f) {
  unsigned int u = __float_as_uint(f);
  return (unsigned short)((u + 0x7FFFu + ((u >> 16) & 1u)) >> 16);  // RNE
}
__device__ __forceinline__ float bf2f(unsigned short s) {
  return __uint_as_float(((unsigned int)s) << 16);
}
__device__ __forceinline__ void gload16(const void* g, void* lds) {
  __builtin_amdgcn_global_load_lds(
      (const __attribute__((address_space(1))) unsigned int*)g,
      (__attribute__((address_space(3))) unsigned int*)lds, 16, 0, 0);
}
// HW barrier that is ALSO a compiler memory fence (asm memory clobber).
__device__ __forceinline__ void barrier_fenced() {
  __builtin_amdgcn_sched_barrier(0);
  asm volatile("s_barrier" ::: "memory");
  __builtin_amdgcn_sched_barrier(0);
}
__device__ __forceinline__ void wait_vm0() {
  asm volatile("s_waitcnt vmcnt(0)" ::: "memory");
}

// ---------------- K1: merged prep — gather_e | pack_w | pack_fcwT ----------------
__global__ void k_prep(const int* __restrict__ iseq, const float* __restrict__ iemb,
                       unsigned short* __restrict__ Ebf,
                       const float* __restrict__ Wh, unsigned short* __restrict__ Wbf,
                       const float* __restrict__ fcW, unsigned short* __restrict__ Bt) {
  __shared__ float tile[32][33];
  const int blk = blockIdx.x;
  if (blk < 1024) {
    int b = blk;
    for (int idx = threadIdx.x; idx < 1600; idx += 256) {  // 50 rows * 32 float4
      int tt = idx >> 5, dq = idx & 31;
      int row = iseq[b * 50 + tt];
      float4 v = *reinterpret_cast<const float4*>(iemb + (size_t)row * 128 + dq * 4);
      unsigned int lo = (unsigned int)f2bf(v.x) | ((unsigned int)f2bf(v.y) << 16);
      unsigned int hi = (unsigned int)f2bf(v.z) | ((unsigned int)f2bf(v.w) << 16);
      *reinterpret_cast<uint2*>(Ebf + (size_t)b * KDIM + tt * 128 + dq * 4) = make_uint2(lo, hi);
    }
  } else if (blk < 1024 + NPAD) {
    int n = blk - 1024;
    unsigned short* dst = Wbf + (size_t)n * KDIM;
    if (n >= NCOL) {
      uint4 z = make_uint4(0, 0, 0, 0);
      for (int idx = threadIdx.x; idx < KDIM / 8; idx += 256)
        reinterpret_cast<uint4*>(dst)[idx] = z;
    } else {
      const float* src = Wh + (size_t)n * KDIM;  // pure row copy: ((l*16+h)*50+i)*128+d == n*6400+k
      for (int idx = threadIdx.x; idx < KDIM / 4; idx += 256) {
        float4 v = reinterpret_cast<const float4*>(src)[idx];
        unsigned int lo = (unsigned int)f2bf(v.x) | ((unsigned int)f2bf(v.y) << 16);
        unsigned int hi = (unsigned int)f2bf(v.z) | ((unsigned int)f2bf(v.w) << 16);
        reinterpret_cast<uint2*>(dst)[idx] = make_uint2(lo, hi);
      }
    }
  } else {
    int idx = blk - 1024 - NPAD;       // 0..231
    int k0 = (idx % 58) * 32, d0 = (idx / 58) * 32;
    int tx = threadIdx.x & 31, ty = threadIdx.x >> 5;  // 32 x 8
#pragma unroll
    for (int it = 0; it < 4; it++) {
      int k = k0 + ty + it * 8;
      tile[ty + it * 8][tx] = (k < 1824) ? fcW[(size_t)k * 128 + d0 + tx] : 0.f;
    }
    __syncthreads();
#pragma unroll
    for (int it = 0; it < 4; it++) {
      int d = d0 + ty + it * 8;
      Bt[(size_t)d * KFC + k0 + tx] = f2bf(tile[tx][ty + it * 8]);
    }
  }
}

// ---------------- K2: conv-as-shifted-GEMM, ONE-S + T3 dbuf pipeline ----------------
// R17 conclusion: 2-barrier structure is at its ~900TF ceiling (863TF, MfmaUtil 37%)
// for BOTH BM=128/256 — only pipeline structure helps now. This combines:
//   - one-s blocks (R13/R14 proven: balanced 1456-block grid, heavy-first, no vmax)
//   - T3-minimum dbuf (R7 loop shape, proven correct): STAGE(next) overlaps
//     COMPUTE(cur); single vmcnt(0)+fenced-barrier per K-step.
// R7's failure was grid imbalance (16-160 K-step blocks), not the pipeline; one-s
// removes that confound. 64KB LDS -> 2 blocks/CU at (256,2), VGPR cap 256 (no spill).
// Natural dispatch: lin = mt + 8*nt + 56*s -> XCD = mt (A-slice L2-resident).
__launch_bounds__(256, 2)
__global__ void k_conv(const unsigned short* __restrict__ Ebf,
                       const unsigned short* __restrict__ Wbf,
                       const float* __restrict__ bh,
                       unsigned int* __restrict__ o_h) {
  __shared__ alignas(16) unsigned short As[2][128 * 64];
  __shared__ alignas(16) unsigned short Bs[2][128 * 64];

  const int tid = threadIdx.x;
  const int wid = tid >> 6, lane = tid & 63;
  const int r = lane & 15, kg = lane >> 4;
  const int wm = wid >> 1, wn = wid & 1;
  const int mt = blockIdx.x, nt = blockIdx.y, s = blockIdx.z;

  const int lmax = min(nt * 8 + 7, 49);
  const int shi = 49 - nt * 8;           // max valid s for this n-tile
  if (s > shi) return;

  const int Rloc = lane >> 3;   // staging: row-in-8 per lane
  const int cph = lane & 7;     // staging: physical 16B chunk per lane

  const f32x4 z4 = {0.f, 0.f, 0.f, 0.f};
  f32x4 acc[4][4];
#pragma unroll
  for (int m = 0; m < 4; m++)
#pragma unroll
    for (int n = 0; n < 4; n++) acc[m][n] = z4;

  // swizzled staging: LDS phys chunk p of row R holds logical chunk (p ^ (R&7))
  auto STAGE = [&](int buf, int kk) {
    const int Rb = wid * 32;
#pragma unroll
    for (int ia = 0; ia < 4; ia++) {
      int R = Rb + ia * 8 + Rloc;
      const unsigned short* src = Ebf + (size_t)(mt * 128 + R) * KDIM + s * 128 + kk * 64
                                      + ((cph ^ (R & 7)) * 8);
      gload16(src, &As[buf][(Rb + ia * 8) * 64]);
    }
#pragma unroll
    for (int ia = 0; ia < 4; ia++) {
      int R = Rb + ia * 8 + Rloc;
      const unsigned short* src = Wbf + (size_t)(nt * 128 + R) * KDIM + kk * 64
                                      + ((cph ^ (R & 7)) * 8);
      gload16(src, &Bs[buf][(Rb + ia * 8) * 64]);
    }
  };

  auto COMPUTE = [&](int buf) {
#pragma unroll
    for (int ks = 0; ks < 2; ks++) {
      bf16x8 af[4], bfr[4];
      const int sw = ((ks * 4 + kg) ^ (r & 7)) * 8;  // swizzled read offset (shorts)
#pragma unroll
      for (int m = 0; m < 4; m++)
        af[m] = *reinterpret_cast<const bf16x8*>(&As[buf][(wm * 64 + m * 16 + r) * 64 + sw]);
#pragma unroll
      for (int n = 0; n < 4; n++)
        bfr[n] = *reinterpret_cast<const bf16x8*>(&Bs[buf][(wn * 64 + n * 16 + r) * 64 + sw]);
#pragma unroll
      for (int m = 0; m < 4; m++)
#pragma unroll
        for (int n = 0; n < 4; n++)
          acc[m][n] = __builtin_amdgcn_mfma_f32_16x16x32_bf16(af[m], bfr[n], acc[m][n], 0, 0, 0);
    }
  };

  const int nk = min(50 - s, lmax + 1) * 2;  // BK-steps (zero-masked i>l terms are free/correct)
  STAGE(0, 0);
  wait_vm0();
  barrier_fenced();
  int cur = 0;
  for (int kk = 0; kk < nk; kk++) {
    if (kk + 1 < nk) STAGE(cur ^ 1, kk + 1);   // prefetch overlaps COMPUTE below
    __builtin_amdgcn_s_setprio(1);
    COMPUTE(cur);
    __builtin_amdgcn_s_setprio(0);
    wait_vm0();         // next buffer fully landed (hidden under compute)
    barrier_fenced();   // all waves done reading cur AND next ready
    cur ^= 1;
  }

  // fused epilogue: relu(conv+bh), validity mask, one atomicMax per element
#pragma unroll
  for (int n = 0; n < 4; n++) {
    int ng = nt * 128 + wn * 64 + n * 16 + r;
    if (ng < NCOL && s <= 49 - (ng >> 4)) {
      float bhv = bh[ng];
#pragma unroll
      for (int m = 0; m < 4; m++) {
        int b = mt * 128 + wm * 64 + m * 16 + kg * 4;
#pragma unroll
        for (int q = 0; q < 4; q++) {
          float v = fmaxf(acc[m][n][q] + bhv, 0.f);
          atomicMax(&o_h[(size_t)(b + q) * NCOL + ng], __float_as_uint(v));
        }
      }
    }
  }
}

// ---------------- K2v: fused o_v compute + o_h convert -> o_bf rows ----------------
__global__ void k_ovcvt(const unsigned short* __restrict__ Ebf,
                        const float* __restrict__ Wv, const float* __restrict__ bv,
                        const unsigned int* __restrict__ o_h,
                        unsigned short* __restrict__ o_bf) {
  int b = blockIdx.x;
  const unsigned short* e = Ebf + (size_t)b * KDIM;
  // part 1: o_bf[b][0:1024] = bf16(sum_t E*Wv + bv)
  for (int rep = 0; rep < 2; rep++) {
    int idx2 = rep * 256 + threadIdx.x;   // uint index, 0..511
    int v = idx2 >> 6;
    int dp = (idx2 & 63) * 2;
    float a0 = bv[v], a1 = a0;
    for (int tt = 0; tt < 50; tt++) {
      float w = Wv[v * 50 + tt];
      a0 += bf2f(e[tt * 128 + dp]) * w;
      a1 += bf2f(e[tt * 128 + dp + 1]) * w;
    }
    unsigned int pk = (unsigned int)f2bf(a0) | ((unsigned int)f2bf(a1) << 16);
    reinterpret_cast<unsigned int*>(o_bf + (size_t)b * KFC)[idx2] = pk;
  }
  // part 2: o_bf[b][1024:1856] = bf16(o_h), zero-padded past 800
  const unsigned int* src = o_h + (size_t)b * NCOL;
  unsigned int* dst = reinterpret_cast<unsigned int*>(o_bf + (size_t)b * KFC + 1024);
  for (int i = threadIdx.x; i < 416; i += 256) {
    int j0 = 2 * i, j1 = j0 + 1;
    unsigned int lo = (j0 < NCOL) ? f2bf(__uint_as_float(src[j0])) : 0;
    unsigned int hi = (j1 < NCOL) ? f2bf(__uint_as_float(src[j1])) : 0;
    dst[i] = lo | (hi << 16);
  }
}

// ---------------- K3: fc partial GEMM, K-split x4, atomicAdd f32 partials ----------------
__launch_bounds__(256, 2)
__global__ void k_fc2(const unsigned short* __restrict__ o_bf,
                      const unsigned short* __restrict__ Bt,
                      float* __restrict__ facc) {
  __shared__ alignas(16) unsigned short As[2][128 * 64];
  __shared__ alignas(16) unsigned short Bs[2][128 * 64];

  const int tid = threadIdx.x;
  const int wid = tid >> 6, lane = tid & 63;
  const int r = lane & 15, kg = lane >> 4;
  const int wm = wid >> 1, wn = wid & 1;
  const int mt = blockIdx.x, kc = blockIdx.y;
  const int kk0 = kc * 8;
  const int nstep = (kc < 3) ? 8 : 5;  // 29 total K-steps

  const int Rloc = lane >> 3;
  const int cph = lane & 7;

  const f32x4 z4 = {0.f, 0.f, 0.f, 0.f};
  f32x4 acc[4][4];
#pragma unroll
  for (int m = 0; m < 4; m++)
#pragma unroll
    for (int n = 0; n < 4; n++) acc[m][n] = z4;

  auto STAGE = [&](int buf, int kk) {
    const int Rb = wid * 32;
#pragma unroll
    for (int ia = 0; ia < 4; ia++) {
      int R = Rb + ia * 8 + Rloc;
      const unsigned short* src = o_bf + (size_t)(mt * 128 + R) * KFC + kk * 64
                                       + ((cph ^ (R & 7)) * 8);
      gload16(src, &As[buf][(Rb + ia * 8) * 64]);
    }
#pragma unroll
    for (int ia = 0; ia < 4; ia++) {
      int R = Rb + ia * 8 + Rloc;
      const unsigned short* src = Bt + (size_t)R * KFC + kk * 64 + ((cph ^ (R & 7)) * 8);
      gload16(src, &Bs[buf][(Rb + ia * 8) * 64]);
    }
  };

  auto COMPUTE = [&](int buf) {
#pragma unroll
    for (int ks = 0; ks < 2; ks++) {
      bf16x8 af[4], bfr[4];
      const int sw = ((ks * 4 + kg) ^ (r & 7)) * 8;
#pragma unroll
      for (int m = 0; m < 4; m++)
        af[m] = *reinterpret_cast<const bf16x8*>(&As[buf][(wm * 64 + m * 16 + r) * 64 + sw]);
#pragma unroll
      for (int n = 0; n < 4; n++)
        bfr[n] = *reinterpret_cast<const bf16x8*>(&Bs[buf][(wn * 64 + n * 16 + r) * 64 + sw]);
#pragma unroll
      for (int m = 0; m < 4; m++)
#pragma unroll
        for (int n = 0; n < 4; n++)
          acc[m][n] = __builtin_amdgcn_mfma_f32_16x16x32_bf16(af[m], bfr[n], acc[m][n], 0, 0, 0);
    }
  };

  int cur = 0;
  STAGE(0, kk0);
  wait_vm0();
  barrier_fenced();
  for (int t = 0; t < nstep; t++) {
    bool has_next = (t + 1 < nstep);
    if (has_next) STAGE(cur ^ 1, kk0 + t + 1);
    __builtin_amdgcn_s_setprio(1);
    COMPUTE(cur);
    __builtin_amdgcn_s_setprio(0);
    wait_vm0();
    barrier_fenced();
    cur ^= 1;
  }

#pragma unroll
  for (int m = 0; m < 4; m++) {
    int b = mt * 128 + wm * 64 + m * 16 + kg * 4;
#pragma unroll
    for (int n = 0; n < 4; n++) {
      int d = wn * 64 + n * 16 + r;
#pragma unroll
      for (int q = 0; q < 4; q++)
        atomicAdd(&facc[(size_t)(b + q) * 128 + d], acc[m][n][q]);
    }
  }
}

// ---------------- K4: finalize fc (bias+relu) + P_u copy, fused ----------------
__global__ void k_fin(const float* __restrict__ facc, const float* __restrict__ fcb,
                      const int* __restrict__ uid, const float* __restrict__ uemb,
                      float* __restrict__ out) {
  int idx = blockIdx.x * 256 + threadIdx.x;  // 1024*256 elems of out
  int b = idx >> 8, c = idx & 255;
  float v;
  if (c < 128) v = fmaxf(facc[(size_t)b * 128 + c] + fcb[c], 0.f);
  else         v = uemb[(size_t)uid[b] * 128 + (c - 128)];
  out[idx] = v;
}

// ---------------- launch ----------------
extern "C" void kernel_launch(void* const* d_in, const int* in_sizes, int n_in,
                              void* d_out, int out_size, void* d_ws, size_t ws_size,
                              hipStream_t stream) {
  const int*   uid  = (const int*)d_in[0];
  const int*   iseq = (const int*)d_in[1];
  const float* uemb = (const float*)d_in[2];
  const float* iemb = (const float*)d_in[3];
  const float* Wv   = (const float*)d_in[4];
  const float* bv   = (const float*)d_in[5];
  const float* Wh   = (const float*)d_in[6];
  const float* bh   = (const float*)d_in[7];
  const float* fcW  = (const float*)d_in[8];
  const float* fcb  = (const float*)d_in[9];
  float* out = (float*)d_out;
  char* ws = (char*)d_ws;

  // layout (28.9 MB peak). o_bf aliases Wbf (written only after k_conv).
  // facc and Bt OUTSIDE Wbf (facc is RMW; Bt written by k_prep while Wbf live).
  unsigned int*   o_h  = (unsigned int*)(ws);                 //  3,276,800 B
  unsigned short* Ebf  = (unsigned short*)(ws + 3276800);     // 13,107,200 B -> 16,384,000
  unsigned short* Wbf  = (unsigned short*)(ws + 16384000);    // 11,468,800 B -> 27,852,800
  unsigned short* o_bf = (unsigned short*)(ws + 16384000);    //  3,801,088 B (alias Wbf, OK)
  float*          facc = (float*)(ws + 27852800);             //    524,288 B -> 28,377,088
  unsigned short* Bt   = (unsigned short*)(ws + 28377088);    //    475,136 B -> 28,852,224

  hipMemsetAsync(o_h, 0, (size_t)1024 * NCOL * 4, stream);
  hipMemsetAsync(facc, 0, (size_t)1024 * 128 * 4, stream);
  k_prep  <<<dim3(1024 + NPAD + 232), 256, 0, stream>>>(iseq, iemb, Ebf, Wh, Wbf, fcW, Bt);
  k_conv  <<<dim3(8, 7, 50), 256, 0, stream>>>(Ebf, Wbf, bh, o_h);
  k_ovcvt <<<dim3(1024), 256, 0, stream>>>(Ebf, Wv, bv, o_h, o_bf);  // o_bf aliases Wbf (dead)
  k_fc2   <<<dim3(8, 4), 256, 0, stream>>>(o_bf, Bt, facc);
  k_fin   <<<dim3(1024), 256, 0, stream>>>(facc, fcb, uid, uemb, out);
}

// Round 20
// 167.113 us; speedup vs baseline: 1.1683x; 1.1388x over previous
//
#include <hip/hip_runtime.h>
#include <stdint.h>

// ---------------- types / helpers ----------------
typedef float  f32x4  __attribute__((ext_vector_type(4)));
typedef short  bf16x8 __attribute__((ext_vector_type(8)));

#define NCOL 800    // L*NH output cols of o_h
#define NPAD 896    // padded to 7*128
#define KDIM 6400   // L*D
#define KFC  1856   // fc K = 1824 padded to 29*64

__device__ __forceinline__ unsigned short f2bf(float f) {
  unsigned int u = __float_as_uint(f);
  return (unsigned short)((u + 0x7FFFu + ((u >> 16) & 1u)) >> 16);  // RNE
}
__device__ __forceinline__ float bf2f(unsigned short s) {
  return __uint_as_float(((unsigned int)s) << 16);
}
__device__ __forceinline__ void gload16(const void* g, void* lds) {
  __builtin_amdgcn_global_load_lds(
      (const __attribute__((address_space(1))) unsigned int*)g,
      (__attribute__((address_space(3))) unsigned int*)lds, 16, 0, 0);
}

// ---------------- K1: merged prep — gather_e | pack_w | pack_fcwT | zero(o_h,facc) ----------------
// blocks [0,1024): Ebf gather+cvt. [1024,1920): Wbf pack. [1920,2152): Bt transpose.
// [2152,2552): zero o_h (400 x 8KB). [2552,2616): zero facc (64 x 8KB).
__global__ void k_prep(const int* __restrict__ iseq, const float* __restrict__ iemb,
                       unsigned short* __restrict__ Ebf,
                       const float* __restrict__ Wh, unsigned short* __restrict__ Wbf,
                       const float* __restrict__ fcW, unsigned short* __restrict__ Bt,
                       unsigned int* __restrict__ o_h, float* __restrict__ facc) {
  __shared__ float tile[32][33];
  const int blk = blockIdx.x;
  if (blk < 1024) {
    int b = blk;
    for (int idx = threadIdx.x; idx < 1600; idx += 256) {  // 50 rows * 32 float4
      int tt = idx >> 5, dq = idx & 31;
      int row = iseq[b * 50 + tt];
      float4 v = *reinterpret_cast<const float4*>(iemb + (size_t)row * 128 + dq * 4);
      unsigned int lo = (unsigned int)f2bf(v.x) | ((unsigned int)f2bf(v.y) << 16);
      unsigned int hi = (unsigned int)f2bf(v.z) | ((unsigned int)f2bf(v.w) << 16);
      *reinterpret_cast<uint2*>(Ebf + (size_t)b * KDIM + tt * 128 + dq * 4) = make_uint2(lo, hi);
    }
  } else if (blk < 1024 + NPAD) {
    int n = blk - 1024;
    unsigned short* dst = Wbf + (size_t)n * KDIM;
    if (n >= NCOL) {
      uint4 z = make_uint4(0, 0, 0, 0);
      for (int idx = threadIdx.x; idx < KDIM / 8; idx += 256)
        reinterpret_cast<uint4*>(dst)[idx] = z;
    } else {
      const float* src = Wh + (size_t)n * KDIM;  // pure row copy: ((l*16+h)*50+i)*128+d == n*6400+k
      for (int idx = threadIdx.x; idx < KDIM / 4; idx += 256) {
        float4 v = reinterpret_cast<const float4*>(src)[idx];
        unsigned int lo = (unsigned int)f2bf(v.x) | ((unsigned int)f2bf(v.y) << 16);
        unsigned int hi = (unsigned int)f2bf(v.z) | ((unsigned int)f2bf(v.w) << 16);
        reinterpret_cast<uint2*>(dst)[idx] = make_uint2(lo, hi);
      }
    }
  } else if (blk < 1024 + NPAD + 232) {
    int idx = blk - 1024 - NPAD;       // 0..231
    int k0 = (idx % 58) * 32, d0 = (idx / 58) * 32;
    int tx = threadIdx.x & 31, ty = threadIdx.x >> 5;  // 32 x 8
#pragma unroll
    for (int it = 0; it < 4; it++) {
      int k = k0 + ty + it * 8;
      tile[ty + it * 8][tx] = (k < 1824) ? fcW[(size_t)k * 128 + d0 + tx] : 0.f;
    }
    __syncthreads();
#pragma unroll
    for (int it = 0; it < 4; it++) {
      int d = d0 + ty + it * 8;
      Bt[(size_t)d * KFC + k0 + tx] = f2bf(tile[tx][ty + it * 8]);
    }
  } else if (blk < 1024 + NPAD + 232 + 400) {
    // zero o_h: 400 blocks x 2048 uints (1024*800 total)
    int base = (blk - 1024 - NPAD - 232) * 2048;
    uint2 z2 = make_uint2(0, 0);
    reinterpret_cast<uint2*>(o_h + base)[threadIdx.x] = z2;
    reinterpret_cast<uint2*>(o_h + base + 512)[threadIdx.x] = z2;
    reinterpret_cast<uint2*>(o_h + base + 1024)[threadIdx.x] = z2;
    reinterpret_cast<uint2*>(o_h + base + 1536)[threadIdx.x] = z2;
  } else {
    // zero facc: 64 blocks x 2048 floats (1024*128 total)
    int base = (blk - 1024 - NPAD - 232 - 400) * 2048;
    float2 z2 = make_float2(0.f, 0.f);
    reinterpret_cast<float2*>(facc + base)[threadIdx.x] = z2;
    reinterpret_cast<float2*>(facc + base + 512)[threadIdx.x] = z2;
    reinterpret_cast<float2*>(facc + base + 1024)[threadIdx.x] = z2;
    reinterpret_cast<float2*>(facc + base + 1536)[threadIdx.x] = z2;
  }
}

// ---------------- K2: conv-as-shifted-GEMM, ONE-S BLOCKS (R14 measured-best) ----------------
// chunk=1: grid (8,7,50), 1456 active blocks of 16-100 K-steps; heaviest first.
// 2-barrier single-32KB-buffer loop at (256,4) = 4 blocks/CU: proven best vs
// dbuf pipelines (R7/R18: 64KB dbuf -> 2 blocks/CU, occupancy 20% < 29%, slower).
// Both BM=128/256 sit at the 2-barrier ~900TF structure ceiling; this is the
// best operating point found for it. Natural dispatch: XCD = mt (A L2-resident).
__launch_bounds__(256, 4)
__global__ void k_conv(const unsigned short* __restrict__ Ebf,
                       const unsigned short* __restrict__ Wbf,
                       const float* __restrict__ bh,
                       unsigned int* __restrict__ o_h) {
  __shared__ alignas(16) unsigned short As[128 * 64];
  __shared__ alignas(16) unsigned short Bs[128 * 64];

  const int tid = threadIdx.x;
  const int wid = tid >> 6, lane = tid & 63;
  const int r = lane & 15, kg = lane >> 4;
  const int wm = wid >> 1, wn = wid & 1;
  const int mt = blockIdx.x, nt = blockIdx.y, s = blockIdx.z;

  const int lmax = min(nt * 8 + 7, 49);
  const int shi = 49 - nt * 8;           // max valid s for this n-tile
  if (s > shi) return;

  const int Rloc = lane >> 3;   // staging: row-in-8 per lane
  const int cph = lane & 7;     // staging: physical 16B chunk per lane

  const f32x4 z4 = {0.f, 0.f, 0.f, 0.f};
  f32x4 acc[4][4];
#pragma unroll
  for (int m = 0; m < 4; m++)
#pragma unroll
    for (int n = 0; n < 4; n++) acc[m][n] = z4;

  // swizzled staging: LDS phys chunk p of row R holds logical chunk (p ^ (R&7))
  auto STAGE = [&](int kk) {
    const int Rb = wid * 32;
#pragma unroll
    for (int ia = 0; ia < 4; ia++) {
      int R = Rb + ia * 8 + Rloc;
      const unsigned short* src = Ebf + (size_t)(mt * 128 + R) * KDIM + s * 128 + kk * 64
                                      + ((cph ^ (R & 7)) * 8);
      gload16(src, &As[(Rb + ia * 8) * 64]);
    }
#pragma unroll
    for (int ia = 0; ia < 4; ia++) {
      int R = Rb + ia * 8 + Rloc;
      const unsigned short* src = Wbf + (size_t)(nt * 128 + R) * KDIM + kk * 64
                                      + ((cph ^ (R & 7)) * 8);
      gload16(src, &Bs[(Rb + ia * 8) * 64]);
    }
  };

  auto COMPUTE = [&]() {
#pragma unroll
    for (int ks = 0; ks < 2; ks++) {
      bf16x8 af[4], bfr[4];
      const int sw = ((ks * 4 + kg) ^ (r & 7)) * 8;  // swizzled read offset (shorts)
#pragma unroll
      for (int m = 0; m < 4; m++)
        af[m] = *reinterpret_cast<const bf16x8*>(&As[(wm * 64 + m * 16 + r) * 64 + sw]);
#pragma unroll
      for (int n = 0; n < 4; n++)
        bfr[n] = *reinterpret_cast<const bf16x8*>(&Bs[(wn * 64 + n * 16 + r) * 64 + sw]);
#pragma unroll
      for (int m = 0; m < 4; m++)
#pragma unroll
        for (int n = 0; n < 4; n++)
          acc[m][n] = __builtin_amdgcn_mfma_f32_16x16x32_bf16(af[m], bfr[n], acc[m][n], 0, 0, 0);
    }
  };

  const int nk = min(50 - s, lmax + 1) * 2;  // BK-steps (zero-masked i>l terms are free/correct)
  for (int kk = 0; kk < nk; kk++) {
    STAGE(kk);
    __syncthreads();
    COMPUTE();
    __syncthreads();
  }

  // fused epilogue: relu(conv+bh), validity mask, one atomicMax per element
#pragma unroll
  for (int n = 0; n < 4; n++) {
    int ng = nt * 128 + wn * 64 + n * 16 + r;
    if (ng < NCOL && s <= 49 - (ng >> 4)) {
      float bhv = bh[ng];
#pragma unroll
      for (int m = 0; m < 4; m++) {
        int b = mt * 128 + wm * 64 + m * 16 + kg * 4;
#pragma unroll
        for (int q = 0; q < 4; q++) {
          float v = fmaxf(acc[m][n][q] + bhv, 0.f);
          atomicMax(&o_h[(size_t)(b + q) * NCOL + ng], __float_as_uint(v));
        }
      }
    }
  }
}

// ---------------- K2v: fused o_v compute + o_h convert -> o_bf rows ----------------
__global__ void k_ovcvt(const unsigned short* __restrict__ Ebf,
                        const float* __restrict__ Wv, const float* __restrict__ bv,
                        const unsigned int* __restrict__ o_h,
                        unsigned short* __restrict__ o_bf) {
  int b = blockIdx.x;
  const unsigned short* e = Ebf + (size_t)b * KDIM;
  // part 1: o_bf[b][0:1024] = bf16(sum_t E*Wv + bv)
  for (int rep = 0; rep < 2; rep++) {
    int idx2 = rep * 256 + threadIdx.x;   // uint index, 0..511
    int v = idx2 >> 6;
    int dp = (idx2 & 63) * 2;
    float a0 = bv[v], a1 = a0;
    for (int tt = 0; tt < 50; tt++) {
      float w = Wv[v * 50 + tt];
      a0 += bf2f(e[tt * 128 + dp]) * w;
      a1 += bf2f(e[tt * 128 + dp + 1]) * w;
    }
    unsigned int pk = (unsigned int)f2bf(a0) | ((unsigned int)f2bf(a1) << 16);
    reinterpret_cast<unsigned int*>(o_bf + (size_t)b * KFC)[idx2] = pk;
  }
  // part 2: o_bf[b][1024:1856] = bf16(o_h), zero-padded past 800
  const unsigned int* src = o_h + (size_t)b * NCOL;
  unsigned int* dst = reinterpret_cast<unsigned int*>(o_bf + (size_t)b * KFC + 1024);
  for (int i = threadIdx.x; i < 416; i += 256) {
    int j0 = 2 * i, j1 = j0 + 1;
    unsigned int lo = (j0 < NCOL) ? f2bf(__uint_as_float(src[j0])) : 0;
    unsigned int hi = (j1 < NCOL) ? f2bf(__uint_as_float(src[j1])) : 0;
    dst[i] = lo | (hi << 16);
  }
}

// ---------------- K3: fc partial GEMM, K-split x4, atomicAdd f32 partials ----------------
__launch_bounds__(256, 2)
__global__ void k_fc2(const unsigned short* __restrict__ o_bf,
                      const unsigned short* __restrict__ Bt,
                      float* __restrict__ facc) {
  __shared__ alignas(16) unsigned short As[2][128 * 64];
  __shared__ alignas(16) unsigned short Bs[2][128 * 64];

  const int tid = threadIdx.x;
  const int wid = tid >> 6, lane = tid & 63;
  const int r = lane & 15, kg = lane >> 4;
  const int wm = wid >> 1, wn = wid & 1;
  const int mt = blockIdx.x, kc = blockIdx.y;
  const int kk0 = kc * 8;
  const int nstep = (kc < 3) ? 8 : 5;  // 29 total K-steps

  const int Rloc = lane >> 3;
  const int cph = lane & 7;

  const f32x4 z4 = {0.f, 0.f, 0.f, 0.f};
  f32x4 acc[4][4];
#pragma unroll
  for (int m = 0; m < 4; m++)
#pragma unroll
    for (int n = 0; n < 4; n++) acc[m][n] = z4;

  auto STAGE = [&](int buf, int kk) {
    const int Rb = wid * 32;
#pragma unroll
    for (int ia = 0; ia < 4; ia++) {
      int R = Rb + ia * 8 + Rloc;
      const unsigned short* src = o_bf + (size_t)(mt * 128 + R) * KFC + kk * 64
                                       + ((cph ^ (R & 7)) * 8);
      gload16(src, &As[buf][(Rb + ia * 8) * 64]);
    }
#pragma unroll
    for (int ia = 0; ia < 4; ia++) {
      int R = Rb + ia * 8 + Rloc;
      const unsigned short* src = Bt + (size_t)R * KFC + kk * 64 + ((cph ^ (R & 7)) * 8);
      gload16(src, &Bs[buf][(Rb + ia * 8) * 64]);
    }
  };

  auto COMPUTE = [&](int buf) {
#pragma unroll
    for (int ks = 0; ks < 2; ks++) {
      bf16x8 af[4], bfr[4];
      const int sw = ((ks * 4 + kg) ^ (r & 7)) * 8;
#pragma unroll
      for (int m = 0; m < 4; m++)
        af[m] = *reinterpret_cast<const bf16x8*>(&As[buf][(wm * 64 + m * 16 + r) * 64 + sw]);
#pragma unroll
      for (int n = 0; n < 4; n++)
        bfr[n] = *reinterpret_cast<const bf16x8*>(&Bs[buf][(wn * 64 + n * 16 + r) * 64 + sw]);
#pragma unroll
      for (int m = 0; m < 4; m++)
#pragma unroll
        for (int n = 0; n < 4; n++)
          acc[m][n] = __builtin_amdgcn_mfma_f32_16x16x32_bf16(af[m], bfr[n], acc[m][n], 0, 0, 0);
    }
  };

  int cur = 0;
  STAGE(0, kk0);
  asm volatile("s_waitcnt vmcnt(0)" ::: "memory");
  __builtin_amdgcn_sched_barrier(0);
  asm volatile("s_barrier" ::: "memory");
  __builtin_amdgcn_sched_barrier(0);
  for (int t = 0; t < nstep; t++) {
    bool has_next = (t + 1 < nstep);
    if (has_next) STAGE(cur ^ 1, kk0 + t + 1);
    __builtin_amdgcn_s_setprio(1);
    COMPUTE(cur);
    __builtin_amdgcn_s_setprio(0);
    asm volatile("s_waitcnt vmcnt(0)" ::: "memory");
    __builtin_amdgcn_sched_barrier(0);
    asm volatile("s_barrier" ::: "memory");
    __builtin_amdgcn_sched_barrier(0);
    cur ^= 1;
  }

#pragma unroll
  for (int m = 0; m < 4; m++) {
    int b = mt * 128 + wm * 64 + m * 16 + kg * 4;
#pragma unroll
    for (int n = 0; n < 4; n++) {
      int d = wn * 64 + n * 16 + r;
#pragma unroll
      for (int q = 0; q < 4; q++)
        atomicAdd(&facc[(size_t)(b + q) * 128 + d], acc[m][n][q]);
    }
  }
}

// ---------------- K4: finalize fc (bias+relu) + P_u copy, fused ----------------
__global__ void k_fin(const float* __restrict__ facc, const float* __restrict__ fcb,
                      const int* __restrict__ uid, const float* __restrict__ uemb,
                      float* __restrict__ out) {
  int idx = blockIdx.x * 256 + threadIdx.x;  // 1024*256 elems of out
  int b = idx >> 8, c = idx & 255;
  float v;
  if (c < 128) v = fmaxf(facc[(size_t)b * 128 + c] + fcb[c], 0.f);
  else         v = uemb[(size_t)uid[b] * 128 + (c - 128)];
  out[idx] = v;
}

// ---------------- launch ----------------
extern "C" void kernel_launch(void* const* d_in, const int* in_sizes, int n_in,
                              void* d_out, int out_size, void* d_ws, size_t ws_size,
                              hipStream_t stream) {
  const int*   uid  = (const int*)d_in[0];
  const int*   iseq = (const int*)d_in[1];
  const float* uemb = (const float*)d_in[2];
  const float* iemb = (const float*)d_in[3];
  const float* Wv   = (const float*)d_in[4];
  const float* bv   = (const float*)d_in[5];
  const float* Wh   = (const float*)d_in[6];
  const float* bh   = (const float*)d_in[7];
  const float* fcW  = (const float*)d_in[8];
  const float* fcb  = (const float*)d_in[9];
  float* out = (float*)d_out;
  char* ws = (char*)d_ws;

  // layout (28.9 MB peak). o_bf aliases Wbf (written only after k_conv).
  // facc and Bt OUTSIDE Wbf (facc is RMW from k_prep's zero; Bt written in k_prep
  // while Wbf live).
  unsigned int*   o_h  = (unsigned int*)(ws);                 //  3,276,800 B
  unsigned short* Ebf  = (unsigned short*)(ws + 3276800);     // 13,107,200 B -> 16,384,000
  unsigned short* Wbf  = (unsigned short*)(ws + 16384000);    // 11,468,800 B -> 27,852,800
  unsigned short* o_bf = (unsigned short*)(ws + 16384000);    //  3,801,088 B (alias Wbf, OK)
  float*          facc = (float*)(ws + 27852800);             //    524,288 B -> 28,377,088
  unsigned short* Bt   = (unsigned short*)(ws + 28377088);    //    475,136 B -> 28,852,224

  k_prep  <<<dim3(1024 + NPAD + 232 + 400 + 64), 256, 0, stream>>>(
              iseq, iemb, Ebf, Wh, Wbf, fcW, Bt, o_h, facc);
  k_conv  <<<dim3(8, 7, 50), 256, 0, stream>>>(Ebf, Wbf, bh, o_h);
  k_ovcvt <<<dim3(1024), 256, 0, stream>>>(Ebf, Wv, bv, o_h, o_bf);  // o_bf aliases Wbf (dead)
  k_fc2   <<<dim3(8, 4), 256, 0, stream>>>(o_bf, Bt, facc);
  k_fin   <<<dim3(1024), 256, 0, stream>>>(facc, fcb, uid, uemb, out);
}